// Round 1
// baseline (13999.126 us; speedup 1.0000x reference)
//
#include <hip/hip_runtime.h>
#include <hip/hip_bf16.h>

#define LYR 6
#define NH 12
#define DM 49
#define NT 16
#define FFD 1024
#define NOUT 10
#define NB 8192
#define NROW (NB * NT)

__device__ __forceinline__ float wsum(float v) {
#pragma unroll
  for (int o = 32; o > 0; o >>= 1) v += __shfl_xor(v, o, 64);
  return v;
}

// ---------------- prep: Wcomb[l][h] = Wo[l,h] @ Wcat[l, h*D:(h+1)*D, :] ----------------
__global__ void prep_comb_kernel(const float* __restrict__ Wo,
                                 const float* __restrict__ Wcat,
                                 float* __restrict__ Wcomb) {
  int lh = blockIdx.x;  // l*NH + h
  int l = lh / NH, hh = lh % NH;
  const float* wo = Wo + (size_t)lh * DM * DM;
  const float* wc = Wcat + ((size_t)l * NH * DM + hh * DM) * DM;
  float* out = Wcomb + (size_t)lh * DM * DM;
  for (int idx = threadIdx.x; idx < DM * DM; idx += blockDim.x) {
    int d = idx / DM, f = idx % DM;
    float acc = 0.f;
    for (int e = 0; e < DM; ++e) acc += wo[d * DM + e] * wc[e * DM + f];
    out[idx] = acc;
  }
}

// bcomb[l] = bcat[l] + sum_{h,d} bo[l,h,d] * Wcat[l, h*D+d, :]
__global__ void prep_bcomb_kernel(const float* __restrict__ bo,
                                  const float* __restrict__ Wcat,
                                  const float* __restrict__ bcat,
                                  float* __restrict__ bcomb) {
  int l = blockIdx.x;
  int f = threadIdx.x;
  if (f >= DM) return;
  float acc = bcat[l * DM + f];
  for (int h = 0; h < NH; ++h)
    for (int d = 0; d < DM; ++d)
      acc += bo[(l * NH + h) * DM + d] *
             Wcat[((size_t)l * NH * DM + h * DM + d) * DM + f];
  bcomb[l * DM + f] = acc;
}

// ---------------- fused LN1 + multi-head attention + combined proj + residual ----------------
// one wave per sample; block = 4 waves
__global__ __launch_bounds__(256) void attn_kernel(
    const float* __restrict__ hin, float* __restrict__ x2out,
    const float* __restrict__ Wq, const float* __restrict__ bq,
    const float* __restrict__ Wk, const float* __restrict__ bk,
    const float* __restrict__ Wv, const float* __restrict__ bv,
    const float* __restrict__ Wcomb, const float* __restrict__ bcomb,
    const float* __restrict__ g1, const float* __restrict__ b1, int layer) {
  __shared__ __align__(16) float lds[4 * 3784];
  const int wave = threadIdx.x >> 6;
  const int lane = threadIdx.x & 63;
  const int sample = blockIdx.x * 4 + wave;
  float* xnT = lds + wave * 3784;  // [49][20]  xn transposed, padded
  float* qoT = xnT + 980;          // q: [16][49] ; later oT: [49][20]
  float* kB = qoT + 980;           // [16][49]
  float* vB = kB + 784;            // [16][49]
  float* pT = vB + 784;            // [16][16]  probs transposed

  const float* hrow = hin + (size_t)sample * (NT * DM);
  const int d = lane;
  const bool act = d < DM;
  const int dc = act ? d : 0;
  const float g = g1[layer * DM + dc];
  const float bt = b1[layer * DM + dc];

  float hreg[NT];
#pragma unroll
  for (int t = 0; t < NT; ++t) {
    float v = act ? hrow[t * DM + d] : 0.f;
    hreg[t] = v;
    float s = wsum(v);
    float s2 = wsum(v * v);
    float mu = s * (1.f / 49.f);
    float var = s2 * (1.f / 49.f) - mu * mu;
    float xn = (v - mu) * rsqrtf(var + 1e-5f) * g + bt;
    if (act) xnT[d * 20 + t] = xn;
  }
  __syncthreads();

  float attnacc[NT];
#pragma unroll
  for (int t = 0; t < NT; ++t) attnacc[t] = 0.f;

  for (int hd = 0; hd < NH; ++hd) {
    const size_t wbase = (size_t)(layer * NH + hd) * DM * DM;
    const float* wq = Wq + wbase;
    const float* wk = Wk + wbase;
    const float* wv = Wv + wbase;
    const int bbase = (layer * NH + hd) * DM + dc;
    float qa[NT], ka[NT], va[NT];
    const float bqv = bq[bbase], bkv = bk[bbase], bvv = bv[bbase];
#pragma unroll
    for (int t = 0; t < NT; ++t) { qa[t] = bqv; ka[t] = bkv; va[t] = bvv; }
    // q,k,v = xn @ W* + b* ; lane = output dim e, shared xn broadcast per d
    for (int dd = 0; dd < DM; ++dd) {
      const float w0 = wq[dd * DM + dc];
      const float w1 = wk[dd * DM + dc];
      const float w2 = wv[dd * DM + dc];
      const float4* xr = (const float4*)(xnT + dd * 20);
      float xs[16];
      ((float4*)xs)[0] = xr[0];
      ((float4*)xs)[1] = xr[1];
      ((float4*)xs)[2] = xr[2];
      ((float4*)xs)[3] = xr[3];
#pragma unroll
      for (int t = 0; t < NT; ++t) {
        qa[t] += xs[t] * w0;
        ka[t] += xs[t] * w1;
        va[t] += xs[t] * w2;
      }
    }
    if (act) {
#pragma unroll
      for (int t = 0; t < NT; ++t) {
        qoT[t * DM + d] = qa[t];
        kB[t * DM + d] = ka[t];
        vB[t * DM + d] = va[t];
      }
    }
    __syncthreads();

    // scores[t][s] = (q[t] . k[s]) / 7, softmax over s ; lane = (t, s%4)
    const int st = lane >> 2, s4 = lane & 3;
    float sc0 = 0.f, sc1 = 0.f, sc2 = 0.f, sc3 = 0.f;
    for (int e = 0; e < DM; ++e) {
      const float qv = qoT[st * DM + e];
      sc0 += qv * kB[(s4 + 0) * DM + e];
      sc1 += qv * kB[(s4 + 4) * DM + e];
      sc2 += qv * kB[(s4 + 8) * DM + e];
      sc3 += qv * kB[(s4 + 12) * DM + e];
    }
    const float scale = 1.f / 7.f;
    sc0 *= scale; sc1 *= scale; sc2 *= scale; sc3 *= scale;
    float m = fmaxf(fmaxf(sc0, sc1), fmaxf(sc2, sc3));
    m = fmaxf(m, __shfl_xor(m, 1, 64));
    m = fmaxf(m, __shfl_xor(m, 2, 64));
    float e0 = __expf(sc0 - m), e1 = __expf(sc1 - m);
    float e2 = __expf(sc2 - m), e3 = __expf(sc3 - m);
    float sum = e0 + e1 + e2 + e3;
    sum += __shfl_xor(sum, 1, 64);
    sum += __shfl_xor(sum, 2, 64);
    const float inv = 1.f / sum;
    pT[(s4 + 0) * NT + st] = e0 * inv;
    pT[(s4 + 4) * NT + st] = e1 * inv;
    pT[(s4 + 8) * NT + st] = e2 * inv;
    pT[(s4 + 12) * NT + st] = e3 * inv;
    __syncthreads();

    // o[t][e] = sum_s p[t][s] * v[s][e] ; lane = e
    float oa[NT];
#pragma unroll
    for (int t = 0; t < NT; ++t) oa[t] = 0.f;
    for (int s = 0; s < NT; ++s) {
      const float vv = vB[s * DM + dc];
      const float4* pr = (const float4*)(pT + s * NT);
      float ps[16];
      ((float4*)ps)[0] = pr[0];
      ((float4*)ps)[1] = pr[1];
      ((float4*)ps)[2] = pr[2];
      ((float4*)ps)[3] = pr[3];
#pragma unroll
      for (int t = 0; t < NT; ++t) oa[t] += ps[t] * vv;
    }
    __syncthreads();
    if (act) {
#pragma unroll
      for (int t = 0; t < NT; ++t) qoT[d * 20 + t] = oa[t];  // oT [49][20]
    }
    __syncthreads();

    // attnacc[t][f] += sum_e o[t][e] * Wcomb[e][f] ; lane = f
    const float* wcb = Wcomb + wbase;
    for (int e = 0; e < DM; ++e) {
      const float w = wcb[e * DM + dc];
      const float4* orow = (const float4*)(qoT + e * 20);
      float os[16];
      ((float4*)os)[0] = orow[0];
      ((float4*)os)[1] = orow[1];
      ((float4*)os)[2] = orow[2];
      ((float4*)os)[3] = orow[3];
#pragma unroll
      for (int t = 0; t < NT; ++t) attnacc[t] += os[t] * w;
    }
    __syncthreads();  // before next head overwrites q/k/v
  }

  if (act) {
    const float bcv = bcomb[layer * DM + d];
    float* orow = x2out + (size_t)sample * (NT * DM);
#pragma unroll
    for (int t = 0; t < NT; ++t) orow[t * DM + d] = hreg[t] + attnacc[t] + bcv;
  }
}

// ---------------- fused LN2 + FeedForward + residual ----------------
__global__ __launch_bounds__(256) void ff_kernel(
    const float* __restrict__ x2in, float* __restrict__ hout,
    const float* __restrict__ W1, const float* __restrict__ b1,
    const float* __restrict__ W2, const float* __restrict__ b2,
    const float* __restrict__ g2, const float* __restrict__ bln, int layer) {
  __shared__ __align__(16) float lds[4 * 2260];
  const int wave = threadIdx.x >> 6;
  const int lane = threadIdx.x & 63;
  const int sample = blockIdx.x * 4 + wave;
  float* xnT = lds + wave * 2260;  // [49][20]
  float* aT = xnT + 980;           // [64][20] relu chunk, transposed

  const float* xrow = x2in + (size_t)sample * (NT * DM);
  const int d = lane;
  const bool act = d < DM;
  const int dc = act ? d : 0;
  const float g = g2[layer * DM + dc];
  const float bt = bln[layer * DM + dc];

  float x2reg[NT];
#pragma unroll
  for (int t = 0; t < NT; ++t) {
    float v = act ? xrow[t * DM + d] : 0.f;
    x2reg[t] = v;
    float s = wsum(v);
    float s2 = wsum(v * v);
    float mu = s * (1.f / 49.f);
    float var = s2 * (1.f / 49.f) - mu * mu;
    float xn = (v - mu) * rsqrtf(var + 1e-5f) * g + bt;
    if (act) xnT[d * 20 + t] = xn;
  }
  __syncthreads();

  float ffacc[NT];
#pragma unroll
  for (int t = 0; t < NT; ++t) ffacc[t] = 0.f;

  const float* w1p = W1 + (size_t)layer * DM * FFD;
  const float* w2p = W2 + (size_t)layer * FFD * DM;
  for (int j0 = 0; j0 < FFD; j0 += 64) {
    // a[t][j] = relu(b1[j] + sum_d xn[t][d] W1[d][j]) ; lane = j
    float aa[NT];
    const float bi = b1[layer * FFD + j0 + lane];
#pragma unroll
    for (int t = 0; t < NT; ++t) aa[t] = bi;
    for (int dd = 0; dd < DM; ++dd) {
      const float w = w1p[dd * FFD + j0 + lane];
      const float4* xr = (const float4*)(xnT + dd * 20);
      float xs[16];
      ((float4*)xs)[0] = xr[0];
      ((float4*)xs)[1] = xr[1];
      ((float4*)xs)[2] = xr[2];
      ((float4*)xs)[3] = xr[3];
#pragma unroll
      for (int t = 0; t < NT; ++t) aa[t] += xs[t] * w;
    }
#pragma unroll
    for (int t = 0; t < NT; ++t) aT[lane * 20 + t] = fmaxf(aa[t], 0.f);
    __syncthreads();
    // ffacc[t][f] += sum_j a[t][j] W2[j][f] ; lane = f
    for (int j = 0; j < 64; ++j) {
      const float w = w2p[(size_t)(j0 + j) * DM + dc];
      const float4* ar = (const float4*)(aT + j * 20);
      float as[16];
      ((float4*)as)[0] = ar[0];
      ((float4*)as)[1] = ar[1];
      ((float4*)as)[2] = ar[2];
      ((float4*)as)[3] = ar[3];
#pragma unroll
      for (int t = 0; t < NT; ++t) ffacc[t] += as[t] * w;
    }
    __syncthreads();  // before overwriting aT next chunk
  }

  if (act) {
    const float b2v = b2[layer * DM + d];
    float* orow = hout + (size_t)sample * (NT * DM);
#pragma unroll
    for (int t = 0; t < NT; ++t) orow[t * DM + d] = x2reg[t] + ffacc[t] + b2v;
  }
}

// ---------------- classification head on token 0 ----------------
__global__ void head_kernel(const float* __restrict__ hfin,
                            const float* __restrict__ Wc,
                            const float* __restrict__ bc,
                            float* __restrict__ out) {
  int idx = blockIdx.x * blockDim.x + threadIdx.x;
  if (idx >= NB * NOUT) return;
  int b = idx / NOUT, c = idx % NOUT;
  const float* hr = hfin + (size_t)b * (NT * DM);  // token 0 row
  float acc = bc[c];
  for (int d = 0; d < DM; ++d) acc += hr[d] * Wc[d * NOUT + c];
  out[idx] = acc;
}

extern "C" void kernel_launch(void* const* d_in, const int* in_sizes, int n_in,
                              void* d_out, int out_size, void* d_ws, size_t ws_size,
                              hipStream_t stream) {
  const float* x = (const float*)d_in[0];
  // d_in[1] = mask (unused by reference)
  const float* Wq = (const float*)d_in[2];
  const float* bq = (const float*)d_in[3];
  const float* Wk = (const float*)d_in[4];
  const float* bk = (const float*)d_in[5];
  const float* Wv = (const float*)d_in[6];
  const float* bv = (const float*)d_in[7];
  const float* Wo = (const float*)d_in[8];
  const float* bo = (const float*)d_in[9];
  const float* Wcat = (const float*)d_in[10];
  const float* bcat = (const float*)d_in[11];
  const float* ln1_g = (const float*)d_in[12];
  const float* ln1_b = (const float*)d_in[13];
  const float* ln2_g = (const float*)d_in[14];
  const float* ln2_b = (const float*)d_in[15];
  const float* W1 = (const float*)d_in[16];
  const float* b1 = (const float*)d_in[17];
  const float* W2 = (const float*)d_in[18];
  const float* b2 = (const float*)d_in[19];
  const float* Wc = (const float*)d_in[20];
  const float* bc = (const float*)d_in[21];

  float* ws = (float*)d_ws;
  float* bufA = ws;                                  // [NROW*DM]
  float* bufB = bufA + (size_t)NROW * DM;            // [NROW*DM]
  float* Wcomb = bufB + (size_t)NROW * DM;           // [LYR*NH*DM*DM]
  float* bcomb = Wcomb + (size_t)LYR * NH * DM * DM; // [LYR*DM]

  prep_comb_kernel<<<LYR * NH, 256, 0, stream>>>(Wo, Wcat, Wcomb);
  prep_bcomb_kernel<<<LYR, 64, 0, stream>>>(bo, Wcat, bcat, bcomb);

  const float* hin = x;  // x.reshape(B, 16, 49) is a flat view
  for (int l = 0; l < LYR; ++l) {
    attn_kernel<<<NB / 4, 256, 0, stream>>>(hin, bufB, Wq, bq, Wk, bk, Wv, bv,
                                            Wcomb, bcomb, ln1_g, ln1_b, l);
    ff_kernel<<<NB / 4, 256, 0, stream>>>(bufB, bufA, W1, b1, W2, b2,
                                          ln2_g, ln2_b, l);
    hin = bufA;
  }
  head_kernel<<<(NB * NOUT + 255) / 256, 256, 0, stream>>>(bufA, Wc, bc,
                                                           (float*)d_out);
}

// Round 2
// 4102.650 us; speedup vs baseline: 3.4122x; 3.4122x over previous
//
#include <hip/hip_runtime.h>

#define LYR 6
#define NH 12
#define DM 49
#define FFD 1024
#define NOUT 10
#define NB 8192

typedef __bf16 bf16x8 __attribute__((ext_vector_type(8)));
typedef unsigned short us8 __attribute__((ext_vector_type(8)));
typedef float f32x4 __attribute__((ext_vector_type(4)));

static __device__ __forceinline__ f32x4 mfma16(us8 a, us8 b, f32x4 c) {
  return __builtin_amdgcn_mfma_f32_16x16x32_bf16(
      __builtin_bit_cast(bf16x8, a), __builtin_bit_cast(bf16x8, b), c, 0, 0, 0);
}

static __device__ __forceinline__ unsigned short f2bf(float f) {
  union { float f; unsigned u; } c; c.f = f;
  unsigned r = c.u + 0x7fffu + ((c.u >> 16) & 1u);
  return (unsigned short)(r >> 16);
}

static __device__ __forceinline__ ushort4 pack4(f32x4 a) {
  ushort4 r;
  r.x = f2bf(a[0]); r.y = f2bf(a[1]); r.z = f2bf(a[2]); r.w = f2bf(a[3]);
  return r;
}

// ---------- prep: transpose/pad/scale weights to bf16 ----------
__global__ void prep_qkv(const float* __restrict__ Wq, const float* __restrict__ Wk,
                         const float* __restrict__ Wv, unsigned short* __restrict__ WqT,
                         unsigned short* __restrict__ WkT, unsigned short* __restrict__ WvT) {
  int lh = blockIdx.x;
  for (int idx = threadIdx.x; idx < 4096; idx += blockDim.x) {
    int e = idx >> 6, d = idx & 63;
    bool ok = (e < DM) && (d < DM);
    float q = ok ? Wq[lh * 2401 + d * DM + e] * (1.f / 7.f) : 0.f;
    float k = ok ? Wk[lh * 2401 + d * DM + e] : 0.f;
    float v = ok ? Wv[lh * 2401 + d * DM + e] : 0.f;
    WqT[lh * 4096 + idx] = f2bf(q);
    WkT[lh * 4096 + idx] = f2bf(k);
    WvT[lh * 4096 + idx] = f2bf(v);
  }
}

__global__ void prep_comb(const float* __restrict__ Wo, const float* __restrict__ Wcat,
                          unsigned short* __restrict__ WcT) {
  int lh = blockIdx.x, l = lh / NH, hh = lh % NH;
  for (int idx = threadIdx.x; idx < 4096; idx += blockDim.x) {
    int f = idx >> 6, e = idx & 63;
    float acc = 0.f;
    if (f < DM && e < DM)
      for (int c = 0; c < DM; ++c)
        acc += Wo[lh * 2401 + e * DM + c] * Wcat[(l * 588 + hh * DM + c) * DM + f];
    WcT[lh * 4096 + idx] = f2bf(acc);
  }
}

__global__ void prep_bcomb(const float* __restrict__ bo, const float* __restrict__ Wcat,
                           const float* __restrict__ bcat, float* __restrict__ bcmb) {
  int l = blockIdx.x, f = threadIdx.x;
  if (f >= 64) return;
  float acc = 0.f;
  if (f < DM) {
    acc = bcat[l * DM + f];
    for (int h = 0; h < NH; ++h)
      for (int c = 0; c < DM; ++c)
        acc += bo[(l * NH + h) * DM + c] * Wcat[(l * 588 + h * DM + c) * DM + f];
  }
  bcmb[l * 64 + f] = acc;
}

__global__ void prep_ff(const float* __restrict__ W1, const float* __restrict__ W2,
                        unsigned short* __restrict__ W1T, unsigned short* __restrict__ W2T) {
  int l = blockIdx.x;
  for (int idx = threadIdx.x; idx < 65536; idx += blockDim.x) {
    int j = idx >> 6, d = idx & 63;
    W1T[l * 65536 + idx] = f2bf(d < DM ? W1[l * DM * FFD + d * FFD + j] : 0.f);
    int f2 = idx >> 10, j2 = idx & 1023;
    W2T[l * 65536 + idx] = f2bf(f2 < DM ? W2[l * FFD * DM + j2 * DM + f2] : 0.f);
  }
}

// ---------- fused 6-layer transformer: 1 sample per wave, no barriers ----------
// Per-wave LDS (ushort units): xn[16][72], qo[16][72], ka[16][72], vT[64][40], p[16][40]
__global__ __launch_bounds__(256, 3) void transformer_kernel(
    const float* __restrict__ x, float* __restrict__ out,
    const unsigned short* __restrict__ WqT, const unsigned short* __restrict__ WkT,
    const unsigned short* __restrict__ WvT, const unsigned short* __restrict__ WcT,
    const unsigned short* __restrict__ W1T, const unsigned short* __restrict__ W2T,
    const float* __restrict__ bq, const float* __restrict__ bk,
    const float* __restrict__ bv, const float* __restrict__ bcmb,
    const float* __restrict__ ln1g, const float* __restrict__ ln1b,
    const float* __restrict__ ln2g, const float* __restrict__ ln2b,
    const float* __restrict__ b1, const float* __restrict__ b2,
    const float* __restrict__ Wc, const float* __restrict__ bc) {
  __shared__ __align__(16) unsigned short sh[4 * 6656];
  const int wv = threadIdx.x >> 6;
  const int lane = threadIdx.x & 63;
  const int g = lane >> 4;    // 0..3
  const int li = lane & 15;   // 0..15
  const int sample = blockIdx.x * 4 + wv;

  unsigned short* Bxn = sh + wv * 6656;
  unsigned short* Bqo = Bxn + 1152;
  unsigned short* Bka = Bqo + 1152;
  unsigned short* BvT = Bka + 1152;
  unsigned short* Bp = BvT + 2560;

  // zero vT+p once (K-padding columns must stay 0 forever)
  {
    ushort4 z; z.x = z.y = z.z = z.w = 0;
    ushort4* zp = (ushort4*)BvT;
    for (int i = lane; i < 800; i += 64) zp[i] = z;
  }

  // h in registers, C-layout: h_[nt][r] = h[row=4g+r][col=li+16nt]; pad cols stay 0
  float h_[4][4];
  {
    const float* xr = x + (size_t)sample * 784;
#pragma unroll
    for (int nt = 0; nt < 4; ++nt) {
      int c = li + 16 * nt;
#pragma unroll
      for (int r = 0; r < 4; ++r)
        h_[nt][r] = (c < DM) ? xr[(4 * g + r) * DM + c] : 0.f;
    }
  }

  for (int layer = 0; layer < LYR; ++layer) {
    // per-layer, per-lane column constants
    float g1v[4], b1v[4], g2v[4], b2v[4], bcv[4], b2f[4];
#pragma unroll
    for (int nt = 0; nt < 4; ++nt) {
      int c = li + 16 * nt;
      bool cv = c < DM;
      g1v[nt] = cv ? ln1g[layer * DM + c] : 0.f;
      b1v[nt] = cv ? ln1b[layer * DM + c] : 0.f;
      g2v[nt] = cv ? ln2g[layer * DM + c] : 0.f;
      b2v[nt] = cv ? ln2b[layer * DM + c] : 0.f;
      bcv[nt] = bcmb[layer * 64 + c];
      b2f[nt] = cv ? b2[layer * DM + c] : 0.f;
    }

    // ---- LN1: h -> xn (LDS, row-major [t][72]) ----
#pragma unroll
    for (int r = 0; r < 4; ++r) {
      float s = 0.f, s2 = 0.f;
#pragma unroll
      for (int nt = 0; nt < 4; ++nt) { float v = h_[nt][r]; s += v; s2 += v * v; }
#pragma unroll
      for (int o = 1; o <= 8; o <<= 1) { s += __shfl_xor(s, o, 64); s2 += __shfl_xor(s2, o, 64); }
      float mu = s * (1.f / 49.f);
      float rs = rsqrtf(s2 * (1.f / 49.f) - mu * mu + 1e-5f);
#pragma unroll
      for (int nt = 0; nt < 4; ++nt) {
        float xnv = (h_[nt][r] - mu) * rs * g1v[nt] + b1v[nt];
        Bxn[(4 * g + r) * 72 + li + 16 * nt] = f2bf(xnv);
      }
    }
    us8 xf0 = *(const us8*)&Bxn[li * 72 + 8 * g];
    us8 xf1 = *(const us8*)&Bxn[li * 72 + 32 + 8 * g];

    // attnacc init with bcomb (residual h added later)
    f32x4 aac[4];
#pragma unroll
    for (int nt = 0; nt < 4; ++nt) { f32x4 t; t[0] = t[1] = t[2] = t[3] = bcv[nt]; aac[nt] = t; }

    for (int hd = 0; hd < NH; ++hd) {
      const int lh = layer * NH + hd;
      const unsigned short* wq = WqT + lh * 4096;
      const unsigned short* wk = WkT + lh * 4096;
      const unsigned short* wvp = WvT + lh * 4096;
      const unsigned short* wc = WcT + lh * 4096;
      const float* bqh = bq + lh * DM;
      const float* bkh = bk + lh * DM;
      const float* bvh = bv + lh * DM;

      // qT, kT: rows e, cols t -> col-major b64 write gives q[t][e], k[t][e]
#pragma unroll
      for (int mi = 0; mi < 4; ++mi) {
        f32x4 accq, acck;
#pragma unroll
        for (int r = 0; r < 4; ++r) {
          int e = 16 * mi + 4 * g + r;
          bool ev = e < DM;
          accq[r] = ev ? bqh[e] * (1.f / 7.f) : 0.f;
          acck[r] = ev ? bkh[e] : 0.f;
        }
        us8 aq0 = *(const us8*)&wq[(16 * mi + li) * 64 + 8 * g];
        us8 aq1 = *(const us8*)&wq[(16 * mi + li) * 64 + 32 + 8 * g];
        accq = mfma16(aq0, xf0, accq);
        accq = mfma16(aq1, xf1, accq);
        us8 ak0 = *(const us8*)&wk[(16 * mi + li) * 64 + 8 * g];
        us8 ak1 = *(const us8*)&wk[(16 * mi + li) * 64 + 32 + 8 * g];
        acck = mfma16(ak0, xf0, acck);
        acck = mfma16(ak1, xf1, acck);
        *(ushort4*)&Bqo[li * 72 + 16 * mi + 4 * g] = pack4(accq);
        *(ushort4*)&Bka[li * 72 + 16 * mi + 4 * g] = pack4(acck);
      }
      // v: rows s, cols e -> col-major write gives vT[e][s]
#pragma unroll
      for (int nt = 0; nt < 4; ++nt) {
        int e0 = li + 16 * nt;
        float bvv = (e0 < DM) ? bvh[e0] : 0.f;
        f32x4 acc; acc[0] = acc[1] = acc[2] = acc[3] = bvv;
        us8 wb0 = *(const us8*)&wvp[(16 * nt + li) * 64 + 8 * g];
        us8 wb1 = *(const us8*)&wvp[(16 * nt + li) * 64 + 32 + 8 * g];
        acc = mfma16(xf0, wb0, acc);
        acc = mfma16(xf1, wb1, acc);
        *(ushort4*)&BvT[(li + 16 * nt) * 40 + 4 * g] = pack4(acc);
      }
      // scoresT[s][t] = sum_d k[s][d] q[t][d]  (scale folded into Wq/bq)
      us8 ka0 = *(const us8*)&Bka[li * 72 + 8 * g];
      us8 ka1 = *(const us8*)&Bka[li * 72 + 32 + 8 * g];
      us8 qb0 = *(const us8*)&Bqo[li * 72 + 8 * g];
      us8 qb1 = *(const us8*)&Bqo[li * 72 + 32 + 8 * g];
      f32x4 sc; sc[0] = sc[1] = sc[2] = sc[3] = 0.f;
      sc = mfma16(ka0, qb0, sc);
      sc = mfma16(ka1, qb1, sc);
      // softmax over s (= rows: 4 regs x 4 g-groups)
      float m = fmaxf(fmaxf(sc[0], sc[1]), fmaxf(sc[2], sc[3]));
      m = fmaxf(m, __shfl_xor(m, 16, 64));
      m = fmaxf(m, __shfl_xor(m, 32, 64));
      float e0 = __expf(sc[0] - m), e1 = __expf(sc[1] - m);
      float e2 = __expf(sc[2] - m), e3 = __expf(sc[3] - m);
      float su = e0 + e1 + e2 + e3;
      su += __shfl_xor(su, 16, 64);
      su += __shfl_xor(su, 32, 64);
      float inv = 1.f / su;
      f32x4 pv; pv[0] = e0 * inv; pv[1] = e1 * inv; pv[2] = e2 * inv; pv[3] = e3 * inv;
      *(ushort4*)&Bp[li * 40 + 4 * g] = pack4(pv);  // p[t][s], s-pad cols stay 0
      // PV: oT[e][t] = sum_s vT[e][s] p[t][s] -> col-major write gives o[t][e] (reuse Bqo)
      us8 pb = *(const us8*)&Bp[li * 40 + 8 * g];
#pragma unroll
      for (int mi = 0; mi < 4; ++mi) {
        us8 av = *(const us8*)&BvT[(16 * mi + li) * 40 + 8 * g];
        f32x4 acc; acc[0] = acc[1] = acc[2] = acc[3] = 0.f;
        acc = mfma16(av, pb, acc);
        *(ushort4*)&Bqo[li * 72 + 16 * mi + 4 * g] = pack4(acc);
      }
      // comb: attnacc[t][f] += sum_e o[t][e] * Wcomb[e][f]
      us8 o0 = *(const us8*)&Bqo[li * 72 + 8 * g];
      us8 o1 = *(const us8*)&Bqo[li * 72 + 32 + 8 * g];
#pragma unroll
      for (int nt = 0; nt < 4; ++nt) {
        us8 w0 = *(const us8*)&wc[(16 * nt + li) * 64 + 8 * g];
        us8 w1 = *(const us8*)&wc[(16 * nt + li) * 64 + 32 + 8 * g];
        aac[nt] = mfma16(o0, w0, aac[nt]);
        aac[nt] = mfma16(o1, w1, aac[nt]);
      }
    }

    // x2 = h + attn (+bcomb already in aac)
#pragma unroll
    for (int nt = 0; nt < 4; ++nt)
#pragma unroll
      for (int r = 0; r < 4; ++r) h_[nt][r] += aac[nt][r];

    // ---- LN2: x2 -> xn2 (reuse Bxn) ----
#pragma unroll
    for (int r = 0; r < 4; ++r) {
      float s = 0.f, s2 = 0.f;
#pragma unroll
      for (int nt = 0; nt < 4; ++nt) { float v = h_[nt][r]; s += v; s2 += v * v; }
#pragma unroll
      for (int o = 1; o <= 8; o <<= 1) { s += __shfl_xor(s, o, 64); s2 += __shfl_xor(s2, o, 64); }
      float mu = s * (1.f / 49.f);
      float rs = rsqrtf(s2 * (1.f / 49.f) - mu * mu + 1e-5f);
#pragma unroll
      for (int nt = 0; nt < 4; ++nt) {
        float xnv = (h_[nt][r] - mu) * rs * g2v[nt] + b2v[nt];
        Bxn[(4 * g + r) * 72 + li + 16 * nt] = f2bf(xnv);
      }
    }
    us8 xf20 = *(const us8*)&Bxn[li * 72 + 8 * g];
    us8 xf21 = *(const us8*)&Bxn[li * 72 + 32 + 8 * g];

    // ffacc init = x2 + b2 (residual + final bias)
    f32x4 ff[4];
#pragma unroll
    for (int nt = 0; nt < 4; ++nt) {
      f32x4 t;
#pragma unroll
      for (int r = 0; r < 4; ++r) t[r] = h_[nt][r] + b2f[nt];
      ff[nt] = t;
    }

    const unsigned short* w2t = W2T + layer * 65536;
    for (int c = 0; c < 16; ++c) {
      const unsigned short* w1t = W1T + layer * 65536 + c * 4096;
      // FF1 (aT): rows j, cols t -> col-major write gives a[t][j] (reuse Bka)
#pragma unroll
      for (int mi = 0; mi < 4; ++mi) {
        f32x4 acc;
#pragma unroll
        for (int r = 0; r < 4; ++r)
          acc[r] = b1[layer * FFD + 64 * c + 16 * mi + 4 * g + r];
        us8 a0 = *(const us8*)&w1t[(16 * mi + li) * 64 + 8 * g];
        us8 a1 = *(const us8*)&w1t[(16 * mi + li) * 64 + 32 + 8 * g];
        acc = mfma16(a0, xf20, acc);
        acc = mfma16(a1, xf21, acc);
#pragma unroll
        for (int r = 0; r < 4; ++r) acc[r] = fmaxf(acc[r], 0.f);
        *(ushort4*)&Bka[li * 72 + 16 * mi + 4 * g] = pack4(acc);
      }
      // FF2: ff[t][f] += sum_j a[t][j] W2[j][f]
      us8 af0 = *(const us8*)&Bka[li * 72 + 8 * g];
      us8 af1 = *(const us8*)&Bka[li * 72 + 32 + 8 * g];
#pragma unroll
      for (int nt = 0; nt < 4; ++nt) {
        us8 w0 = *(const us8*)&w2t[(16 * nt + li) * 1024 + 64 * c + 8 * g];
        us8 w1 = *(const us8*)&w2t[(16 * nt + li) * 1024 + 64 * c + 32 + 8 * g];
        ff[nt] = mfma16(af0, w0, ff[nt]);
        ff[nt] = mfma16(af1, w1, ff[nt]);
      }
    }

    // h = x2 + ffn
#pragma unroll
    for (int nt = 0; nt < 4; ++nt)
#pragma unroll
      for (int r = 0; r < 4; ++r) h_[nt][r] = ff[nt][r];
  }

  // ---- classification head on token 0 ----
  float* hs = (float*)BvT;  // reuse vT region as fp32 scratch
  if (g == 0) {
#pragma unroll
    for (int nt = 0; nt < 4; ++nt) {
      int c = li + 16 * nt;
      if (c < DM) hs[c] = h_[nt][0];
    }
  }
  if (lane < NOUT) {
    float acc = bc[lane];
    for (int d = 0; d < DM; ++d) acc += hs[d] * Wc[d * NOUT + lane];
    out[(size_t)sample * NOUT + lane] = acc;
  }
}

extern "C" void kernel_launch(void* const* d_in, const int* in_sizes, int n_in,
                              void* d_out, int out_size, void* d_ws, size_t ws_size,
                              hipStream_t stream) {
  const float* x = (const float*)d_in[0];
  const float* Wq = (const float*)d_in[2];
  const float* bq = (const float*)d_in[3];
  const float* Wk = (const float*)d_in[4];
  const float* bk = (const float*)d_in[5];
  const float* Wv = (const float*)d_in[6];
  const float* bv = (const float*)d_in[7];
  const float* Wo = (const float*)d_in[8];
  const float* bo = (const float*)d_in[9];
  const float* Wcat = (const float*)d_in[10];
  const float* bcat = (const float*)d_in[11];
  const float* ln1_g = (const float*)d_in[12];
  const float* ln1_b = (const float*)d_in[13];
  const float* ln2_g = (const float*)d_in[14];
  const float* ln2_b = (const float*)d_in[15];
  const float* W1 = (const float*)d_in[16];
  const float* b1 = (const float*)d_in[17];
  const float* W2 = (const float*)d_in[18];
  const float* b2 = (const float*)d_in[19];
  const float* Wc = (const float*)d_in[20];
  const float* bc = (const float*)d_in[21];

  unsigned short* WqT = (unsigned short*)d_ws;
  unsigned short* WkT = WqT + 72 * 4096;
  unsigned short* WvT = WkT + 72 * 4096;
  unsigned short* WcT = WvT + 72 * 4096;
  unsigned short* W1T = WcT + 72 * 4096;
  unsigned short* W2T = W1T + 6 * 65536;
  float* bcmb = (float*)(W2T + 6 * 65536);

  prep_qkv<<<72, 256, 0, stream>>>(Wq, Wk, Wv, WqT, WkT, WvT);
  prep_comb<<<72, 256, 0, stream>>>(Wo, Wcat, WcT);
  prep_bcomb<<<6, 64, 0, stream>>>(bo, Wcat, bcat, bcmb);
  prep_ff<<<6, 256, 0, stream>>>(W1, W2, W1T, W2T);

  transformer_kernel<<<NB / 4, 256, 0, stream>>>(
      x, (float*)d_out, WqT, WkT, WvT, WcT, W1T, W2T, bq, bk, bv, bcmb,
      ln1_g, ln1_b, ln2_g, ln2_b, b1, b2, Wc, bc);
}